// Round 7
// baseline (336.285 us; speedup 1.0000x reference)
//
#include <hip/hip_runtime.h>

typedef __bf16 bf16x8 __attribute__((ext_vector_type(8)));
typedef __bf16 bf16x4 __attribute__((ext_vector_type(4)));
typedef float f32x4 __attribute__((ext_vector_type(4)));
typedef float f32x16 __attribute__((ext_vector_type(16)));
typedef unsigned int u32;

__device__ __forceinline__ f32x4 mfma16(bf16x8 a, bf16x8 b, f32x4 c) {
  return __builtin_amdgcn_mfma_f32_16x16x32_bf16(a, b, c, 0, 0, 0);
}
__device__ __forceinline__ f32x16 mfma32(bf16x8 a, bf16x8 b, f32x16 c) {
  return __builtin_amdgcn_mfma_f32_32x32x16_bf16(a, b, c, 0, 0, 0);
}
__device__ __forceinline__ bf16x8 ldv(const __bf16* p) { return *(const bf16x8*)p; }
__device__ __forceinline__ u32 pk2(float a, float b) {
  union { __bf16 h[2]; u32 u; } c;
  c.h[0] = (__bf16)a; c.h[1] = (__bf16)b;
  return c.u;
}
__device__ __forceinline__ bf16x8 frag4(u32 a, u32 b, u32 c, u32 d) {
  union { u32 u[4]; bf16x8 v; } f;
  f.u[0] = a; f.u[1] = b; f.u[2] = c; f.u[3] = d;
  return f.v;
}

// ---------------------------------------------------------------------------
// K0: convert Wf(32x256) | Wg(32x256) | Wh(256x256) fp32 -> Wb bf16 [320][256]
// ---------------------------------------------------------------------------
__global__ void wcvt_kernel(const float* __restrict__ Wf, const float* __restrict__ Wg,
                            const float* __restrict__ Wh, __bf16* __restrict__ Wb) {
  int i = blockIdx.x * 256 + threadIdx.x;  // 0..81919
  float v;
  if (i < 8192)       v = Wf[i];
  else if (i < 16384) v = Wg[i - 8192];
  else                v = Wh[i - 16384];
  Wb[i] = (__bf16)v;
}

// ---------------------------------------------------------------------------
// K1: projections, single-barrier version. Grid 512 = b(4) x ntile(128 of 32).
// 256 thr = 4 waves. Phase 1: stage WHOLE x-tile (256c x 32n fp32, 32KB) into
// LDS transposed as bf16 (one pass, high MLP). One barrier. Phase 2: 80
// uninterrupted mfma16 per wave (wave w owns o-range w*80..+79).
//   o<64  -> fgT[b][n][o]   bf16 (Q|K fragment layout)
//   o>=64 -> hb[b][o-64][n] bf16 (j-contiguous, via LDS transpose)
// ---------------------------------------------------------------------------
__global__ __launch_bounds__(256) void proj_kernel(
    const float* __restrict__ x, const float* __restrict__ bfv,
    const float* __restrict__ bgv, const float* __restrict__ bhv,
    const __bf16* __restrict__ Wb, __bf16* __restrict__ fgT,
    __bf16* __restrict__ hb) {
  __shared__ __align__(16) char smem[16896 + 18432];
  __bf16* xT = (__bf16*)smem;             // [32 n][264 c] bf16 (pad 8)
  __bf16* ho = (__bf16*)(smem + 16896);   // [256 c][36 n] bf16

  const int t = threadIdx.x;
  const int l = t & 63, w = t >> 6, q = l >> 4, l15 = l & 15;
  const int bi = blockIdx.x;
  const int b = bi >> 7;
  const int n0 = (bi & 127) << 5;

  const float* xb = x + (size_t)b * 256 * 4096;

  // stage + transpose: 8 passes x (32 rows, 8 float4/row)
#pragma unroll
  for (int pass = 0; pass < 8; ++pass) {
    int c = pass * 32 + (t >> 3);
    int nn = (t & 7) * 4;
    float4 v = *(const float4*)(xb + (size_t)c * 4096 + n0 + nn);
    xT[(nn + 0) * 264 + c] = (__bf16)v.x;
    xT[(nn + 1) * 264 + c] = (__bf16)v.y;
    xT[(nn + 2) * 264 + c] = (__bf16)v.z;
    xT[(nn + 3) * 264 + c] = (__bf16)v.w;
  }
  __syncthreads();

  f32x4 acc[2][5] = {};
  const __bf16* wp0 = Wb + (size_t)(w * 80 + l15) * 256 + q * 8;
#pragma unroll
  for (int kc = 0; kc < 8; ++kc) {
    bf16x8 bfr[5];
#pragma unroll
    for (int ot = 0; ot < 5; ot++)
      bfr[ot] = ldv(wp0 + kc * 32 + (size_t)ot * 16 * 256);
#pragma unroll
    for (int nh = 0; nh < 2; ++nh) {
      bf16x8 af = ldv(xT + (nh * 16 + l15) * 264 + kc * 32 + q * 8);
#pragma unroll
      for (int ot = 0; ot < 5; ot++)
        acc[nh][ot] = mfma16(af, bfr[ot], acc[nh][ot]);
    }
  }

  // bias + dual-layout store
#pragma unroll
  for (int ot = 0; ot < 5; ot++) {
    int o = w * 80 + ot * 16 + l15;
    float bias = (o < 32) ? bfv[o] : (o < 64) ? bgv[o - 32] : bhv[o - 64];
#pragma unroll
    for (int nh = 0; nh < 2; ++nh)
#pragma unroll
      for (int r = 0; r < 4; r++) {
        int n_rel = nh * 16 + q * 4 + r;
        float val = acc[nh][ot][r] + bias;
        if (o < 64) {
          fgT[((size_t)b * 4096 + n0 + n_rel) * 64 + o] = (__bf16)val;
        } else {
          ho[(o - 64) * 36 + n_rel] = (__bf16)val;
        }
      }
  }
  __syncthreads();
  unsigned short* hbu = (unsigned short*)hb + (size_t)b * 256 * 4096 + n0;
  const unsigned short* hou = (const unsigned short*)ho;
  for (int e = t; e < 4096; e += 256) {
    int c = e >> 4, nn = (e & 15) * 2;
    unsigned int vv = *(const unsigned int*)(hou + c * 36 + nn);
    *(unsigned int*)(hbu + (size_t)c * 4096 + nn) = vv;
  }
}

// ---------------------------------------------------------------------------
// K2: fused attention — ZERO barriers, ZERO LDS. One wave = one complete
// (b, jp, i32) task: S^T = K·Q^T (C-layout cols = i = lanes), raw exp
// (|s|<~40 << 88: no online max; split-j partials are exact), in-register
// C-layout -> B-operand transform (4 shfl_xor(32) + cndmasks per tile, since
// both layouts share col=lane&31), then O^T[c][i] += V·P^T with acc 8xf32x16
// (full 256c, complete output — no cross-wave reduction, no atomics).
// V and K for step s+1 prefetched into registers during step s (~1000 cy of
// cover, nothing can drain it — no barriers exist). 2048 independent waves.
// ---------------------------------------------------------------------------
__global__ __launch_bounds__(256, 2) void attn_kernel(
    const __bf16* __restrict__ fgT, const __bf16* __restrict__ hb,
    __bf16* __restrict__ pO, float* __restrict__ Lp) {
  const int t = threadIdx.x;
  const int l = t & 63, w = t >> 6;
  const int h = l >> 5, l31 = l & 31;

  const int bi = blockIdx.x;
  const int xcd = bi & 7, slot = bi >> 3;      // slot 0..63
  const int combo = xcd * 2 + (slot & 1);      // (b,jp) pinned to one XCD's L2
  const int b = combo >> 2, jp = combo & 3;
  const int i0 = (slot >> 1) * 128 + w * 32;   // wave's private i-tile

  const __bf16* fgb = fgT + (size_t)b * 4096 * 64;
  const __bf16* hbb = hb + (size_t)b * 256 * 4096;
  const int jq0 = jp << 10;

  // Q (B-operand, loop-invariant): B[k][n=i]: n=lane&31, k=h*8+e
  const __bf16* qp = fgb + (size_t)(i0 + l31) * 64 + h * 8;
  const bf16x8 qf0 = ldv(qp);
  const bf16x8 qf1 = ldv(qp + 16);

  f32x16 acc[8] = {};
  float rs = 0.f;

  // C-layout tile -> exp -> two PV B-frags (kc_loc 0,1) via h-half exchange
  const bool hi = (h != 0);
  auto mkfrags = [&](const f32x16& s, bf16x8& fA, bf16x8& fB) {
    float p[16];
#pragma unroll
    for (int r = 0; r < 16; r++) { p[r] = __expf(s[r]); rs += p[r]; }
    u32 q0a = pk2(p[0], p[1]),   q0b = pk2(p[2], p[3]);
    u32 q1a = pk2(p[4], p[5]),   q1b = pk2(p[6], p[7]);
    u32 q2a = pk2(p[8], p[9]),   q2b = pk2(p[10], p[11]);
    u32 q3a = pk2(p[12], p[13]), q3b = pk2(p[14], p[15]);
    {
      u32 sa = hi ? q0a : q1a, sb = hi ? q0b : q1b;   // send group 2*0+(1-h)
      u32 ra = __shfl_xor(sa, 32), rb = __shfl_xor(sb, 32);
      u32 oa = hi ? q1a : q0a, ob_ = hi ? q1b : q0b;  // keep group 2*0+h
      fA = frag4(hi ? ra : oa, hi ? rb : ob_, hi ? oa : ra, hi ? ob_ : rb);
    }
    {
      u32 sa = hi ? q2a : q3a, sb = hi ? q2b : q3b;
      u32 ra = __shfl_xor(sa, 32), rb = __shfl_xor(sb, 32);
      u32 oa = hi ? q3a : q2a, ob_ = hi ? q3b : q2b;
      fB = frag4(hi ? ra : oa, hi ? rb : ob_, hi ? oa : ra, hi ? ob_ : rb);
    }
  };

  // one 64-j step; vcur holds this step's V (4 kc x 8 ci), vnxt/knxt get s+1
  auto do_step = [&](int step, bf16x8 (&vcur)[4][8], bf16x8 (&vnxt)[4][8],
                     bf16x8 (&kcur)[2][2], bf16x8 (&knxt)[2][2]) {
    // S^T tiles (A=K: m=lane=j; B=Q: n=lane=i)
    f32x16 s0 = {}, s1 = {};
    s0 = mfma32(kcur[0][0], qf0, s0);
    s0 = mfma32(kcur[0][1], qf1, s0);
    s1 = mfma32(kcur[1][0], qf0, s1);
    s1 = mfma32(kcur[1][1], qf1, s1);
    // K prefetch (step+1)
    if (step < 15) {
      const __bf16* kp = fgb + (size_t)(jq0 + (step + 1) * 64 + l31) * 64 + 32 + h * 8;
      knxt[0][0] = ldv(kp);        knxt[0][1] = ldv(kp + 16);
      knxt[1][0] = ldv(kp + 2048); knxt[1][1] = ldv(kp + 2064);
    }
    // V prefetch (step+1): A[m=c][k=j]: lane=c, k=h*8+e
    {
      int sn = (step < 15) ? step + 1 : 0;  // wrap load harmless
      const __bf16* vp = hbb + (size_t)l31 * 4096 + jq0 + sn * 64 + h * 8;
#pragma unroll
      for (int kc = 0; kc < 4; kc++)
#pragma unroll
        for (int ci = 0; ci < 8; ci++)
          vnxt[kc][ci] = ldv(vp + (size_t)ci * 32 * 4096 + kc * 16);
    }
    // exp + pack + h-exchange -> 4 B-frags
    bf16x8 pf[4];
    mkfrags(s0, pf[0], pf[1]);
    mkfrags(s1, pf[2], pf[3]);
    // PV: 4 k-chunks x 8 c-tiles
#pragma unroll
    for (int kc = 0; kc < 4; kc++)
#pragma unroll
      for (int ci = 0; ci < 8; ci++)
        acc[ci] = mfma32(vcur[kc][ci], pf[kc], acc[ci]);
  };

  // preload step 0
  bf16x8 va[4][8], vb_[4][8], ka[2][2], kb[2][2];
  {
    const __bf16* kp = fgb + (size_t)(jq0 + l31) * 64 + 32 + h * 8;
    ka[0][0] = ldv(kp);        ka[0][1] = ldv(kp + 16);
    ka[1][0] = ldv(kp + 2048); ka[1][1] = ldv(kp + 2064);
    const __bf16* vp = hbb + (size_t)l31 * 4096 + jq0 + h * 8;
#pragma unroll
    for (int kc = 0; kc < 4; kc++)
#pragma unroll
      for (int ci = 0; ci < 8; ci++)
        va[kc][ci] = ldv(vp + (size_t)ci * 32 * 4096 + kc * 16);
  }

#pragma unroll 1
  for (int s2 = 0; s2 < 8; ++s2) {
    do_step(2 * s2,     va,  vb_, ka, kb);
    do_step(2 * s2 + 1, vb_, va,  kb, ka);
  }

  // rowsum finalize: column i = i0+l31 split across h-halves
  rs += __shfl_xor(rs, 32);
  if (h == 0) Lp[(size_t)(jp * 4 + b) * 4096 + i0 + l31] = rs;

  // store partial O^T (C-layout: col=i in lanes -> contiguous 64B runs)
  __bf16* ob = pO + (size_t)(jp * 4 + b) * 256 * 4096;
#pragma unroll
  for (int ci = 0; ci < 8; ci++)
#pragma unroll
    for (int r = 0; r < 16; r++) {
      int c = ci * 32 + (r & 3) + 8 * (r >> 2) + 4 * h;
      ob[(size_t)c * 4096 + i0 + l31] = (__bf16)acc[ci][r];
    }
}

// ---------------------------------------------------------------------------
// K3: combine partials + normalize + residual.
//   out[b][c][i] = gamma * (sum_jp pO[jp][b][c][i]) / (sum_jp Lp[jp][b][i]) + x
// ---------------------------------------------------------------------------
__global__ __launch_bounds__(256) void norm_kernel(
    const float* __restrict__ x, const float* __restrict__ gamma_p,
    const __bf16* __restrict__ pO, const float* __restrict__ Lp,
    float* __restrict__ out) {
  const int bc = blockIdx.x;           // b = bc>>8, c = bc&255
  const int b = bc >> 8;
  const float gm = gamma_p[0];
  const float* xr = x + (size_t)bc * 4096;
  float* orow = out + (size_t)bc * 4096;
  const __bf16* pbase = pO + (size_t)bc * 4096;   // +jp*4194304
  const float* lbase = Lp + (size_t)b * 4096;     // +jp*16384

  for (int i0 = threadIdx.x * 4; i0 < 4096; i0 += 1024) {
    float4 xv = *(const float4*)(xr + i0);
    float s0 = 0.f, s1 = 0.f, s2 = 0.f, s3 = 0.f;
    float l0 = 0.f, l1 = 0.f, l2 = 0.f, l3 = 0.f;
#pragma unroll
    for (int jp = 0; jp < 4; jp++) {
      bf16x4 pv = *(const bf16x4*)(pbase + (size_t)jp * 4194304 + i0);
      s0 += (float)pv[0]; s1 += (float)pv[1]; s2 += (float)pv[2]; s3 += (float)pv[3];
      float4 lv = *(const float4*)(lbase + (size_t)jp * 16384 + i0);
      l0 += lv.x; l1 += lv.y; l2 += lv.z; l3 += lv.w;
    }
    float4 ov;
    ov.x = gm * s0 / l0 + xv.x;
    ov.y = gm * s1 / l1 + xv.y;
    ov.z = gm * s2 / l2 + xv.z;
    ov.w = gm * s3 / l3 + xv.w;
    *(float4*)(orow + i0) = ov;
  }
}

// ---------------------------------------------------------------------------
extern "C" void kernel_launch(void* const* d_in, const int* in_sizes, int n_in,
                              void* d_out, int out_size, void* d_ws, size_t ws_size,
                              hipStream_t stream) {
  const float* x   = (const float*)d_in[0];
  const float* Wf  = (const float*)d_in[1];
  const float* bfv = (const float*)d_in[2];
  const float* Wg  = (const float*)d_in[3];
  const float* bgv = (const float*)d_in[4];
  const float* Wh  = (const float*)d_in[5];
  const float* bhv = (const float*)d_in[6];
  const float* gm  = (const float*)d_in[7];
  float* out = (float*)d_out;

  char* ws = (char*)d_ws;
  __bf16* Wb  = (__bf16*)ws;                      //   160 KiB  @ 0
  __bf16* fgT = (__bf16*)(ws + 262144);           //  2 MiB: [4][4096][64]
  __bf16* hb  = (__bf16*)(ws + 2359296);          //  8 MiB: [4][256][4096]
  __bf16* pO  = (__bf16*)(ws + 10747904);         // 32 MiB: [4jp][4][256][4096] bf16
  float*  Lp  = (float*)(ws + 44302336);          // 256 KiB: [4jp][4][4096] fp32

  hipLaunchKernelGGL(wcvt_kernel, dim3(320), dim3(256), 0, stream, Wf, Wg, Wh, Wb);
  hipLaunchKernelGGL(proj_kernel, dim3(512), dim3(256), 0, stream,
                     x, bfv, bgv, bhv, Wb, fgT, hb);
  hipLaunchKernelGGL(attn_kernel, dim3(512), dim3(256), 0, stream,
                     fgT, hb, pO, Lp);
  hipLaunchKernelGGL(norm_kernel, dim3(1024), dim3(256), 0, stream,
                     x, gm, pO, Lp, out);
}

// Round 8
// 279.837 us; speedup vs baseline: 1.2017x; 1.2017x over previous
//
#include <hip/hip_runtime.h>

typedef __bf16 bf16x8 __attribute__((ext_vector_type(8)));
typedef __bf16 bf16x4 __attribute__((ext_vector_type(4)));
typedef float f32x4 __attribute__((ext_vector_type(4)));
typedef float f32x16 __attribute__((ext_vector_type(16)));
typedef unsigned int u32;

__device__ __forceinline__ f32x4 mfma16(bf16x8 a, bf16x8 b, f32x4 c) {
  return __builtin_amdgcn_mfma_f32_16x16x32_bf16(a, b, c, 0, 0, 0);
}
__device__ __forceinline__ f32x16 mfma32(bf16x8 a, bf16x8 b, f32x16 c) {
  return __builtin_amdgcn_mfma_f32_32x32x16_bf16(a, b, c, 0, 0, 0);
}
__device__ __forceinline__ bf16x8 ldv(const __bf16* p) { return *(const bf16x8*)p; }
__device__ __forceinline__ u32 pk2(float a, float b) {
  union { __bf16 h[2]; u32 u; } c;
  c.h[0] = (__bf16)a; c.h[1] = (__bf16)b;
  return c.u;
}
__device__ __forceinline__ bf16x8 frag4(u32 a, u32 b, u32 c, u32 d) {
  union { u32 u[4]; bf16x8 v; } f;
  f.u[0] = a; f.u[1] = b; f.u[2] = c; f.u[3] = d;
  return f.v;
}

// ---------------------------------------------------------------------------
// K0: convert Wf(32x256) | Wg(32x256) | Wh(256x256) fp32 -> Wb bf16 [320][256]
// ---------------------------------------------------------------------------
__global__ void wcvt_kernel(const float* __restrict__ Wf, const float* __restrict__ Wg,
                            const float* __restrict__ Wh, __bf16* __restrict__ Wb) {
  int i = blockIdx.x * 256 + threadIdx.x;  // 0..81919
  float v;
  if (i < 8192)       v = Wf[i];
  else if (i < 16384) v = Wg[i - 8192];
  else                v = Wh[i - 16384];
  Wb[i] = (__bf16)v;
}

// ---------------------------------------------------------------------------
// K1: projections, single-barrier version (validated R7). Grid 512 =
// b(4) x ntile(128 of 32). 256 thr = 4 waves. Phase 1: stage whole x-tile
// (256c x 32n fp32) into LDS transposed as bf16. One barrier. Phase 2: 80
// uninterrupted mfma16 per wave (wave w owns o-range w*80..+79).
//   o<64  -> fgT[b][n][o]   bf16 (Q|K fragment layout)
//   o>=64 -> hb[b][o-64][n] bf16 (j-contiguous, via LDS transpose)
// ---------------------------------------------------------------------------
__global__ __launch_bounds__(256) void proj_kernel(
    const float* __restrict__ x, const float* __restrict__ bfv,
    const float* __restrict__ bgv, const float* __restrict__ bhv,
    const __bf16* __restrict__ Wb, __bf16* __restrict__ fgT,
    __bf16* __restrict__ hb) {
  __shared__ __align__(16) char smem[16896 + 18432];
  __bf16* xT = (__bf16*)smem;             // [32 n][264 c] bf16 (pad 8)
  __bf16* ho = (__bf16*)(smem + 16896);   // [256 c][36 n] bf16

  const int t = threadIdx.x;
  const int l = t & 63, w = t >> 6, q = l >> 4, l15 = l & 15;
  const int bi = blockIdx.x;
  const int b = bi >> 7;
  const int n0 = (bi & 127) << 5;

  const float* xb = x + (size_t)b * 256 * 4096;

  // stage + transpose: 8 passes x (32 rows, 8 float4/row)
#pragma unroll
  for (int pass = 0; pass < 8; ++pass) {
    int c = pass * 32 + (t >> 3);
    int nn = (t & 7) * 4;
    float4 v = *(const float4*)(xb + (size_t)c * 4096 + n0 + nn);
    xT[(nn + 0) * 264 + c] = (__bf16)v.x;
    xT[(nn + 1) * 264 + c] = (__bf16)v.y;
    xT[(nn + 2) * 264 + c] = (__bf16)v.z;
    xT[(nn + 3) * 264 + c] = (__bf16)v.w;
  }
  __syncthreads();

  f32x4 acc[2][5] = {};
  const __bf16* wp0 = Wb + (size_t)(w * 80 + l15) * 256 + q * 8;
#pragma unroll
  for (int kc = 0; kc < 8; ++kc) {
    bf16x8 bfr[5];
#pragma unroll
    for (int ot = 0; ot < 5; ot++)
      bfr[ot] = ldv(wp0 + kc * 32 + (size_t)ot * 16 * 256);
#pragma unroll
    for (int nh = 0; nh < 2; ++nh) {
      bf16x8 af = ldv(xT + (nh * 16 + l15) * 264 + kc * 32 + q * 8);
#pragma unroll
      for (int ot = 0; ot < 5; ot++)
        acc[nh][ot] = mfma16(af, bfr[ot], acc[nh][ot]);
    }
  }

  // bias + dual-layout store
#pragma unroll
  for (int ot = 0; ot < 5; ot++) {
    int o = w * 80 + ot * 16 + l15;
    float bias = (o < 32) ? bfv[o] : (o < 64) ? bgv[o - 32] : bhv[o - 64];
#pragma unroll
    for (int nh = 0; nh < 2; ++nh)
#pragma unroll
      for (int r = 0; r < 4; r++) {
        int n_rel = nh * 16 + q * 4 + r;
        float val = acc[nh][ot][r] + bias;
        if (o < 64) {
          fgT[((size_t)b * 4096 + n0 + n_rel) * 64 + o] = (__bf16)val;
        } else {
          ho[(o - 64) * 36 + n_rel] = (__bf16)val;
        }
      }
  }
  __syncthreads();
  unsigned short* hbu = (unsigned short*)hb + (size_t)b * 256 * 4096 + n0;
  const unsigned short* hou = (const unsigned short*)ho;
  for (int e = t; e < 4096; e += 256) {
    int c = e >> 4, nn = (e & 15) * 2;
    unsigned int vv = *(const unsigned int*)(hou + c * 36 + nn);
    *(unsigned int*)(hbu + (size_t)c * 4096 + nn) = vv;
  }
}

// ---------------------------------------------------------------------------
// K2: fused attention — zero barriers, zero LDS (math validated in R7),
// register budget FIXED. Wave task = (b, jp, i32-tile, c64-quadrant):
// the 4 waves of a block share one i-tile (QK + exp replicated x4 — cheap vs
// PV) so per-wave state is small:
//   acc 2xf32x16 = 32 AGPR; V rolling single-buffer 8 frags = 32 VGPR;
//   K 4+Q 2 frags; ONE S tile live (tile-serial transform) = 16.
//   Total ~150 < 170 cap at launch_bounds(256,3) -> 3 waves/SIMD, NO spills.
// Per 64-j step: S^T tile = K·Q^T (C-layout cols = i = lanes), raw exp
// (|s|<~40 << 88), in-register C->B-operand transform (shfl_xor h-halves),
// PV: acc[ci] += V·P^T. V/K for step+1 reloaded in-place right after last
// use (~600 cy cover, nothing can drain it — no barriers exist).
// 8192 independent waves; (b,jp) pinned per-XCD for V/K L2 residency.
// ---------------------------------------------------------------------------
__global__ __launch_bounds__(256, 3) void attn_kernel(
    const __bf16* __restrict__ fgT, const __bf16* __restrict__ hb,
    __bf16* __restrict__ pO, float* __restrict__ Lp) {
  const int t = threadIdx.x;
  const int l = t & 63, w = t >> 6;            // w = c-quadrant 0..3
  const int h = l >> 5, l31 = l & 31;

  const int bi = blockIdx.x;
  const int xcd = bi & 7, rest = bi >> 3;      // rest 0..255
  const int combo = xcd * 2 + (rest & 1);      // (b,jp) pinned to one XCD
  const int b = combo >> 2, jp = combo & 3;
  const int i0 = (rest >> 1) << 5;             // i-tile base (32 rows)

  const __bf16* fgb = fgT + (size_t)b * 4096 * 64;
  const __bf16* hbb = hb + (size_t)b * 256 * 4096;
  const int jq0 = jp << 10;

  // Q (B-operand, loop-invariant): n=lane&31=i, k=h*8+e (+16 second frag)
  const __bf16* qp = fgb + (size_t)(i0 + l31) * 64 + h * 8;
  const bf16x8 qf0 = ldv(qp);
  const bf16x8 qf1 = ldv(qp + 16);

  f32x16 acc[2] = {};
  float rs = 0.f;
  const bool hi = (h != 0);

  // C-layout S tile -> exp -> two PV B-frags via h-half exchange (R7-validated)
  auto mkfrags = [&](const f32x16& s, bf16x8& fA, bf16x8& fB) {
    float p[16];
#pragma unroll
    for (int r = 0; r < 16; r++) { p[r] = __expf(s[r]); rs += p[r]; }
    u32 q0a = pk2(p[0], p[1]),   q0b = pk2(p[2], p[3]);
    u32 q1a = pk2(p[4], p[5]),   q1b = pk2(p[6], p[7]);
    u32 q2a = pk2(p[8], p[9]),   q2b = pk2(p[10], p[11]);
    u32 q3a = pk2(p[12], p[13]), q3b = pk2(p[14], p[15]);
    {
      u32 sa = hi ? q0a : q1a, sb = hi ? q0b : q1b;
      u32 ra = __shfl_xor(sa, 32), rb = __shfl_xor(sb, 32);
      u32 oa = hi ? q1a : q0a, ob_ = hi ? q1b : q0b;
      fA = frag4(hi ? ra : oa, hi ? rb : ob_, hi ? oa : ra, hi ? ob_ : rb);
    }
    {
      u32 sa = hi ? q2a : q3a, sb = hi ? q2b : q3b;
      u32 ra = __shfl_xor(sa, 32), rb = __shfl_xor(sb, 32);
      u32 oa = hi ? q3a : q2a, ob_ = hi ? q3b : q2b;
      fB = frag4(hi ? ra : oa, hi ? rb : ob_, hi ? oa : ra, hi ? ob_ : rb);
    }
  };

  // V rolling buffer: lane = c row (w*64 + ci*32 + l31), k = h*8+e
  const __bf16* vbase = hbb + (size_t)(w * 64 + l31) * 4096 + h * 8;
  // K rolling buffer: lane = j row, A-operand
  bf16x8 ka00, ka01, ka10, ka11;
  bf16x8 vf[4][2];
  {
    const __bf16* kp = fgb + (size_t)(jq0 + l31) * 64 + 32 + h * 8;
    ka00 = ldv(kp);        ka01 = ldv(kp + 16);
    ka10 = ldv(kp + 2048); ka11 = ldv(kp + 2064);
#pragma unroll
    for (int kc = 0; kc < 4; kc++) {
      vf[kc][0] = ldv(vbase + jq0 + kc * 16);
      vf[kc][1] = ldv(vbase + (size_t)32 * 4096 + jq0 + kc * 16);
    }
  }

#pragma unroll 1
  for (int step = 0; step < 16; ++step) {
    const int jn = jq0 + (((step + 1) & 15) << 6);   // next step (wrap harmless)
    const __bf16* kp = fgb + (size_t)(jn + l31) * 64 + 32 + h * 8;

    bf16x8 pf[4];
    // S tile 0 (j 0..31 of this step) -> pf[0..1]; reload K right after use
    {
      f32x16 s = {};
      s = mfma32(ka00, qf0, s);
      s = mfma32(ka01, qf1, s);
      ka00 = ldv(kp); ka01 = ldv(kp + 16);
      mkfrags(s, pf[0], pf[1]);
    }
    // S tile 1 (j 32..63) -> pf[2..3]
    {
      f32x16 s = {};
      s = mfma32(ka10, qf0, s);
      s = mfma32(ka11, qf1, s);
      ka10 = ldv(kp + 2048); ka11 = ldv(kp + 2064);
      mkfrags(s, pf[2], pf[3]);
    }
    // PV: acc[ci] += V·P^T; reload V slot right after last use
#pragma unroll
    for (int kc = 0; kc < 4; kc++) {
      acc[0] = mfma32(vf[kc][0], pf[kc], acc[0]);
      acc[1] = mfma32(vf[kc][1], pf[kc], acc[1]);
      vf[kc][0] = ldv(vbase + jn + kc * 16);
      vf[kc][1] = ldv(vbase + (size_t)32 * 4096 + jn + kc * 16);
    }
  }

  // rowsum for column i = i0+l31 (split across h halves); identical in all 4
  // waves (replicated S) -> only wave 0 writes
  rs += __shfl_xor(rs, 32);
  if (w == 0 && h == 0)
    Lp[(size_t)(jp * 4 + b) * 4096 + i0 + l31] = rs;

  // store partial O^T (C-layout: col=i in lanes -> 64B contiguous runs)
  __bf16* ob = pO + (size_t)(jp * 4 + b) * 256 * 4096;
#pragma unroll
  for (int ci = 0; ci < 2; ci++)
#pragma unroll
    for (int r = 0; r < 16; r++) {
      int c = w * 64 + ci * 32 + (r & 3) + 8 * (r >> 2) + 4 * h;
      ob[(size_t)c * 4096 + i0 + l31] = (__bf16)acc[ci][r];
    }
}

// ---------------------------------------------------------------------------
// K3: combine partials + normalize + residual.
//   out[b][c][i] = gamma * (sum_jp pO[jp][b][c][i]) / (sum_jp Lp[jp][b][i]) + x
// ---------------------------------------------------------------------------
__global__ __launch_bounds__(256) void norm_kernel(
    const float* __restrict__ x, const float* __restrict__ gamma_p,
    const __bf16* __restrict__ pO, const float* __restrict__ Lp,
    float* __restrict__ out) {
  const int bc = blockIdx.x;           // b = bc>>8, c = bc&255
  const int b = bc >> 8;
  const float gm = gamma_p[0];
  const float* xr = x + (size_t)bc * 4096;
  float* orow = out + (size_t)bc * 4096;
  const __bf16* pbase = pO + (size_t)bc * 4096;   // +jp*4194304
  const float* lbase = Lp + (size_t)b * 4096;     // +jp*16384

  for (int i0 = threadIdx.x * 4; i0 < 4096; i0 += 1024) {
    float4 xv = *(const float4*)(xr + i0);
    float s0 = 0.f, s1 = 0.f, s2 = 0.f, s3 = 0.f;
    float l0 = 0.f, l1 = 0.f, l2 = 0.f, l3 = 0.f;
#pragma unroll
    for (int jp = 0; jp < 4; jp++) {
      bf16x4 pv = *(const bf16x4*)(pbase + (size_t)jp * 4194304 + i0);
      s0 += (float)pv[0]; s1 += (float)pv[1]; s2 += (float)pv[2]; s3 += (float)pv[3];
      float4 lv = *(const float4*)(lbase + (size_t)jp * 16384 + i0);
      l0 += lv.x; l1 += lv.y; l2 += lv.z; l3 += lv.w;
    }
    float4 ov;
    ov.x = gm * s0 / l0 + xv.x;
    ov.y = gm * s1 / l1 + xv.y;
    ov.z = gm * s2 / l2 + xv.z;
    ov.w = gm * s3 / l3 + xv.w;
    *(float4*)(orow + i0) = ov;
  }
}

// ---------------------------------------------------------------------------
extern "C" void kernel_launch(void* const* d_in, const int* in_sizes, int n_in,
                              void* d_out, int out_size, void* d_ws, size_t ws_size,
                              hipStream_t stream) {
  const float* x   = (const float*)d_in[0];
  const float* Wf  = (const float*)d_in[1];
  const float* bfv = (const float*)d_in[2];
  const float* Wg  = (const float*)d_in[3];
  const float* bgv = (const float*)d_in[4];
  const float* Wh  = (const float*)d_in[5];
  const float* bhv = (const float*)d_in[6];
  const float* gm  = (const float*)d_in[7];
  float* out = (float*)d_out;

  char* ws = (char*)d_ws;
  __bf16* Wb  = (__bf16*)ws;                      //   160 KiB  @ 0
  __bf16* fgT = (__bf16*)(ws + 262144);           //  2 MiB: [4][4096][64]
  __bf16* hb  = (__bf16*)(ws + 2359296);          //  8 MiB: [4][256][4096]
  __bf16* pO  = (__bf16*)(ws + 10747904);         // 32 MiB: [4jp][4][256][4096] bf16
  float*  Lp  = (float*)(ws + 44302336);          // 256 KiB: [4jp][4][4096] fp32

  hipLaunchKernelGGL(wcvt_kernel, dim3(320), dim3(256), 0, stream, Wf, Wg, Wh, Wb);
  hipLaunchKernelGGL(proj_kernel, dim3(512), dim3(256), 0, stream,
                     x, bfv, bgv, bhv, Wb, fgT, hb);
  hipLaunchKernelGGL(attn_kernel, dim3(2048), dim3(256), 0, stream,
                     fgT, hb, pO, Lp);
  hipLaunchKernelGGL(norm_kernel, dim3(1024), dim3(256), 0, stream,
                     x, gm, pO, Lp, out);
}